// Round 8
// baseline (378.736 us; speedup 1.0000x reference)
//
#include <hip/hip_runtime.h>

// Problem constants
#define B_   4
#define NQ_  2048
#define NKV_ 2048
#define H_   16
#define DK_  64
#define DM_  1024
#define DKV_ 2048   // stacked K|V projection width

typedef _Float16 f16x8 __attribute__((ext_vector_type(8)));
typedef _Float16 f16x4 __attribute__((ext_vector_type(4)));
typedef _Float16 f16x2 __attribute__((ext_vector_type(2)));
typedef float    f32x4 __attribute__((ext_vector_type(4)));
typedef float    f32x16 __attribute__((ext_vector_type(16)));
typedef unsigned u32x2 __attribute__((ext_vector_type(2)));
typedef unsigned u32x4 __attribute__((ext_vector_type(4)));

__device__ __forceinline__ void gload_lds16(const void* g, void* l) {
  __builtin_amdgcn_global_load_lds(
      (const __attribute__((address_space(1))) unsigned int*)g,
      (__attribute__((address_space(3))) unsigned int*)l, 16, 0, 0);
}

// ---------------- cast f32 -> f16 (4 elems/thread) ----------------
__global__ __launch_bounds__(256) void cast_f16(const float* __restrict__ in,
                                                _Float16* __restrict__ out, int n4) {
  int i = blockIdx.x * 256 + threadIdx.x;
  if (i >= n4) return;
  float4 v = ((const float4*)in)[i];
  f16x4 o = {(_Float16)v.x, (_Float16)v.y, (_Float16)v.z, (_Float16)v.w};
  *(f16x4*)(out + (size_t)i * 4) = o;
}

// ---------------- W [K][N] f32 -> Wt [N][K] f16 ----------------
__global__ __launch_bounds__(256) void wtrans(const float* __restrict__ W,
                                              _Float16* __restrict__ Wt) {
  __shared__ float tile[32][33];
  int bx = blockIdx.x & 31, by = blockIdx.x >> 5;
  int tx = threadIdx.x & 31, ty = threadIdx.x >> 5;  // ty 0..7
#pragma unroll
  for (int j = 0; j < 4; ++j)
    tile[ty + j * 8][tx] = W[(size_t)(by * 32 + ty + j * 8) * 1024 + bx * 32 + tx];
  __syncthreads();
#pragma unroll
  for (int j = 0; j < 4; ++j)
    Wt[(size_t)(bx * 32 + ty + j * 8) * 1024 + by * 32 + tx] = (_Float16)tile[tx][ty + j * 8];
}

// ---------------- GEMM: C[M][N] = A[M][K] @ Bt[N][K]^T (m97 structure) ----------------
template <int F32OUT>
__global__ __launch_bounds__(256, 2) void gemm_bt(const _Float16* __restrict__ A,
                                                  const _Float16* __restrict__ Bt,
                                                  void* __restrict__ Cp,
                                                  int M, int N, int K) {
  __shared__ _Float16 As[128 * 32];
  __shared__ _Float16 Bs[128 * 32];
  const int nbn = N >> 7;
  const int bm = blockIdx.x / nbn, bn = blockIdx.x % nbn;
  const int t = threadIdx.x, w = t >> 6, l = t & 63;
  const int lr = l & 15, lg = l >> 4;
  const int wr = w >> 1, wc = w & 1;
  const int m0 = bm << 7, n0 = bn << 7;

  f32x4 acc[4][4] = {};

  for (int k0 = 0; k0 < K; k0 += 32) {
#pragma unroll
    for (int p = 0; p < 2; ++p) {
      int off = p * 4096 + w * 1024 + l * 16;  // linear byte offset in 8KB tile
      int row = off >> 6;                       // 64B per row (32 f16)
      int col = (off & 63) >> 1;                // element col
      gload_lds16(A  + (size_t)(m0 + row) * K + k0 + col, (char*)As + p * 4096 + w * 1024);
      gload_lds16(Bt + (size_t)(n0 + row) * K + k0 + col, (char*)Bs + p * 4096 + w * 1024);
    }
    __syncthreads();
    f16x8 af[4], bq[4];
#pragma unroll
    for (int i = 0; i < 4; ++i) {
      af[i] = *(const f16x8*)((const char*)As + (wr * 64 + i * 16 + lr) * 64 + lg * 16);
      bq[i] = *(const f16x8*)((const char*)Bs + (wc * 64 + i * 16 + lr) * 64 + lg * 16);
    }
#pragma unroll
    for (int i = 0; i < 4; ++i)
#pragma unroll
      for (int j = 0; j < 4; ++j)
        acc[i][j] = __builtin_amdgcn_mfma_f32_16x16x32_f16(af[i], bq[j], acc[i][j], 0, 0, 0);
    __syncthreads();
  }
#pragma unroll
  for (int i = 0; i < 4; ++i)
#pragma unroll
    for (int j = 0; j < 4; ++j)
#pragma unroll
      for (int r = 0; r < 4; ++r) {
        size_t row = m0 + wr * 64 + i * 16 + lg * 4 + r;
        size_t col = n0 + wc * 64 + j * 16 + lr;
        if (F32OUT) ((float*)Cp)[row * N + col] = acc[i][j][r];
        else ((_Float16*)Cp)[row * N + col] = (_Float16)acc[i][j][r];
      }
}

// ---------------- V [b][kv][1024+h*64+d] -> Vt [b][h][d][kv] ----------------
__global__ __launch_bounds__(256) void vtrans(const _Float16* __restrict__ KVb,
                                              _Float16* __restrict__ Vt) {
  __shared__ _Float16 tile[64][72];  // [kv][d], padded rows (144B, 16B-aligned)
  int idx = blockIdx.x;
  int kt = idx & 31, h = (idx >> 5) & 15, b = idx >> 9;
  int kv0 = kt << 6;
  int t = threadIdx.x;
#pragma unroll
  for (int p = 0; p < 2; ++p) {
    int c = t + p * 256;
    int row = c >> 3, cb = (c & 7) * 16;
    f16x8 v = *(const f16x8*)(KVb + (size_t)(b * NKV_ + kv0 + row) * DKV_ + 1024 + h * 64 + cb / 2);
    *(f16x8*)((char*)&tile[row][0] + cb) = v;
  }
  __syncthreads();
  int d = t & 63, j0 = (t >> 6) * 2;
#pragma unroll
  for (int jj = 0; jj < 2; ++jj) {
    int kvs = (j0 + jj) * 8;
    f16x8 o;
#pragma unroll
    for (int u = 0; u < 8; ++u) o[u] = tile[kvs + u][d];
    *(f16x8*)(Vt + ((size_t)((b * H_ + h) * 64 + d)) * NKV_ + kv0 + kvs) = o;
  }
}

__device__ __forceinline__ void plswap(unsigned& a, unsigned& b) {
  u32x2 r = __builtin_amdgcn_permlane32_swap(a, b, false, false);
  a = r[0];
  b = r[1];
}

// ---------------- fused attention: softmax(Q K^T + bias) V ----------------
// 32x32x16 MFMA, swapped operands. Block = 128 q (4 waves x 32 q), KVBLK=64.
// S^T = mfma(K,Q): lane holds S[kv][q=lane&31] (16 regs per 32-kv subtile).
// P^T PV B-fragment built IN-REGISTER via cvt_pkrtz + permlane32_swap (no P LDS).
// Single-buffer 16KB LDS (K,V), issue-early/write-late staging, 2 barriers/iter.
__global__ __launch_bounds__(256, 4) void attn(const _Float16* __restrict__ Qb,
                                               const _Float16* __restrict__ KVb,
                                               const _Float16* __restrict__ Vt,
                                               const float* __restrict__ bias,
                                               _Float16* __restrict__ ctx) {
  __shared__ _Float16 Ks[64 * 64];   // [kv][d], XOR-swizzled rows (128B)
  __shared__ _Float16 Vs[64 * 64];   // [d][kv], XOR-swizzled rows
  const float LOG2E = 1.44269504f;
  int idx = blockIdx.x;
  int b = idx & 3, qt = (idx >> 2) & 15, hd = idx >> 6;  // batch innermost: bias L2/L3 reuse
  int t = threadIdx.x, w = t >> 6, l = t & 63;
  int lq = l & 31, h = l >> 5;       // mfma col (q), lane-half (k-group)
  int qw = (qt << 7) + (w << 5);     // wave's 32 q rows

  // Q B-fragments: qf[ks] = Q[qw+lq][d = ks*16 + h*8 + 0..7], scaled by log2(e)
  f16x8 qf[4];
  {
    const _Float16* qp = Qb + ((size_t)(b * NQ_ + qw + lq)) * DM_ + hd * 64 + h * 8;
#pragma unroll
    for (int ks = 0; ks < 4; ++ks) {
      qf[ks] = *(const f16x8*)(qp + ks * 16);
#pragma unroll
      for (int u = 0; u < 8; ++u) qf[ks][u] = qf[ks][u] * (_Float16)LOG2E;
    }
  }

  f32x16 acc[2] = {};   // acc^T[d-tile][reg]: d = (reg&3)+8*(reg>>2)+4h+32*dt, q = lq
  float mrow = -1e30f, lsum = 0.f;

  const _Float16* Kbase = KVb + (size_t)b * NKV_ * DKV_ + hd * 64;
  const _Float16* Vtb   = Vt + (size_t)(b * H_ + hd) * 64 * NKV_;
  const float*    biasrow = bias + ((size_t)hd * NQ_ + qw + lq) * NKV_ + 4 * h;

  const int srow = t >> 3;        // staging row (p adds 32)
  const int scb  = (t & 7) * 16;  // staging byte col within 128B row

  f16x8 kreg[2], vreg[2];

  auto LOADKV = [&](int kv0) {
#pragma unroll
    for (int p = 0; p < 2; ++p) {
      int row = srow + p * 32;
      kreg[p] = *(const f16x8*)(Kbase + (size_t)(kv0 + row) * DKV_ + scb / 2);
      vreg[p] = *(const f16x8*)(Vtb + (size_t)row * NKV_ + kv0 + scb / 2);
    }
  };

  LOADKV(0);

  for (int it = 0; it < 32; ++it) {
    const int kv0 = it << 6;

    // ---- write staged regs (tile it) to LDS ----
#pragma unroll
    for (int p = 0; p < 2; ++p) {
      int row = srow + p * 32;
      int off = (row * 128 + scb) ^ ((row & 7) << 4);
      *(f16x8*)((char*)Ks + off) = kreg[p];
      *(f16x8*)((char*)Vs + off) = vreg[p];
    }
    __syncthreads();

    // ---- issue next tile's global loads (consumed next iteration) ----
    LOADKV((it < 31) ? kv0 + 64 : kv0);

    // ---- two 32-kv subtiles ----
#pragma unroll
    for (int T = 0; T < 2; ++T) {
      // bias: 4x float4, kv = kv0 + 32T + 8g + 4h + {0..3}
      const float* bp = biasrow + kv0 + 32 * T;
      float4 bv[4];
#pragma unroll
      for (int g = 0; g < 4; ++g) bv[g] = *(const float4*)(bp + 8 * g);

      // S^T = K Q^T over 4 k-steps (d), exp2 domain
      f32x16 s = {};
      const int krow = 32 * T + lq;
      const int ksw = (krow & 7) << 4;
      __builtin_amdgcn_s_setprio(1);
#pragma unroll
      for (int ks = 0; ks < 4; ++ks) {
        f16x8 kf = *(const f16x8*)((char*)Ks + ((krow * 128 + ks * 32 + h * 16) ^ ksw));
        s = __builtin_amdgcn_mfma_f32_32x32x16_f16(kf, qf[ks], s, 0, 0, 0);
      }
      __builtin_amdgcn_s_setprio(0);

      // + bias (exp2 domain)
#pragma unroll
      for (int g = 0; g < 4; ++g) {
        s[4 * g + 0] = fmaf(bv[g].x, LOG2E, s[4 * g + 0]);
        s[4 * g + 1] = fmaf(bv[g].y, LOG2E, s[4 * g + 1]);
        s[4 * g + 2] = fmaf(bv[g].z, LOG2E, s[4 * g + 2]);
        s[4 * g + 3] = fmaf(bv[g].w, LOG2E, s[4 * g + 3]);
      }

      // row max: 15 in-lane + 1 cross-half shuffle (lanes l, l^32 share q)
      float pmax = s[0];
#pragma unroll
      for (int r = 1; r < 16; ++r) pmax = fmaxf(pmax, s[r]);
      pmax = fmaxf(pmax, __shfl_xor(pmax, 32));

      // defer-max: rescale only when max grew past THR=8 (P <= 2^8, f16-safe)
      if (__any(pmax > mrow + 8.0f)) {
        float mn = fmaxf(mrow, pmax);
        float corr = exp2f(mrow - mn);
        mrow = mn;
        lsum *= corr;
#pragma unroll
        for (int r = 0; r < 16; ++r) { acc[0][r] *= corr; acc[1][r] *= corr; }
      }

      // P = exp2(S - mrow); sum: 15 in-lane + 1 shuffle
      float rs = 0.f;
#pragma unroll
      for (int r = 0; r < 16; ++r) {
        float p = exp2f(s[r] - mrow);
        s[r] = p;
        rs += p;
      }
      rs += __shfl_xor(rs, 32);
      lsum += rs;

      // pack P to f16 dwords: dw[g][j] covers kv = 8g+4h+2j+{0,1} (+32T)
      unsigned dw[4][2];
#pragma unroll
      for (int g = 0; g < 4; ++g)
#pragma unroll
        for (int j = 0; j < 2; ++j)
          dw[g][j] = __builtin_bit_cast(unsigned,
              __builtin_amdgcn_cvt_pkrtz(s[4 * g + 2 * j], s[4 * g + 2 * j + 1]));

      // PV: pf built in-register via permlane32_swap; acc^T += V^T-frag x P^T-frag
      __builtin_amdgcn_s_setprio(1);
#pragma unroll
      for (int kp = 0; kp < 2; ++kp) {
        unsigned A0 = dw[2 * kp][0], B0 = dw[2 * kp + 1][0];
        unsigned A1 = dw[2 * kp][1], B1 = dw[2 * kp + 1][1];
        plswap(A0, B0);
        plswap(A1, B1);
        u32x4 pv4 = {A0, A1, B0, B1};
        f16x8 pf = __builtin_bit_cast(f16x8, pv4);
        const int kvs = (2 * T + kp) * 32 + h * 16;
#pragma unroll
        for (int dt = 0; dt < 2; ++dt) {
          int vrow = 32 * dt + lq;
          f16x8 vf = *(const f16x8*)((char*)Vs + ((vrow * 128 + kvs) ^ ((vrow & 7) << 4)));
          acc[dt] = __builtin_amdgcn_mfma_f32_32x32x16_f16(vf, pf, acc[dt], 0, 0, 0);
        }
      }
      __builtin_amdgcn_s_setprio(0);
    }
    __syncthreads();
  }

  // ---- normalize + write ctx[b][q=qw+lq][hd*64 + d] (8B stores) ----
  float inv = 1.0f / lsum;
  _Float16* cp = ctx + ((size_t)b * NQ_ + qw + lq) * DM_ + hd * 64 + 4 * h;
#pragma unroll
  for (int dt = 0; dt < 2; ++dt)
#pragma unroll
    for (int g = 0; g < 4; ++g) {
      f16x4 o = {(_Float16)(acc[dt][4 * g + 0] * inv), (_Float16)(acc[dt][4 * g + 1] * inv),
                 (_Float16)(acc[dt][4 * g + 2] * inv), (_Float16)(acc[dt][4 * g + 3] * inv)};
      *(f16x4*)(cp + 32 * dt + 8 * g) = o;
    }
}

extern "C" void kernel_launch(void* const* d_in, const int* in_sizes, int n_in,
                              void* d_out, int out_size, void* d_ws, size_t ws_size,
                              hipStream_t stream) {
  const float* x    = (const float*)d_in[0];
  const float* enc  = (const float*)d_in[1];
  const float* bias = (const float*)d_in[2];
  const float* Wq   = (const float*)d_in[3];
  const float* Wk   = (const float*)d_in[4];
  const float* Wv   = (const float*)d_in[5];
  const float* Wo   = (const float*)d_in[6];
  char* ws = (char*)d_ws;
  const size_t MiB = 1024 * 1024;
  _Float16* WqT   = (_Float16*)(ws + 0 * MiB);
  _Float16* WkT   = (_Float16*)(ws + 2 * MiB);   // WkT+WvT contiguous: stacked Bt [2048][1024]
  _Float16* WvT   = (_Float16*)(ws + 4 * MiB);
  _Float16* WoT   = (_Float16*)(ws + 6 * MiB);
  _Float16* xf    = (_Float16*)(ws + 8 * MiB);
  _Float16* encf  = (_Float16*)(ws + 24 * MiB);
  _Float16* Qb    = (_Float16*)(ws + 40 * MiB);
  _Float16* KVb   = (_Float16*)(ws + 56 * MiB);  // [8192][2048]: cols 0..1023=K, 1024..2047=V
  _Float16* Vt    = (_Float16*)(ws + 88 * MiB);  // [B][H][64][NKV]
  _Float16* ctxf  = (_Float16*)(ws + 104 * MiB); // [8192][1024]

  wtrans<<<1024, 256, 0, stream>>>(Wq, WqT);
  wtrans<<<1024, 256, 0, stream>>>(Wk, WkT);
  wtrans<<<1024, 256, 0, stream>>>(Wv, WvT);
  wtrans<<<1024, 256, 0, stream>>>(Wo, WoT);
  cast_f16<<<8192, 256, 0, stream>>>(x, xf, 2097152);
  cast_f16<<<8192, 256, 0, stream>>>(enc, encf, 2097152);
  gemm_bt<0><<<512, 256, 0, stream>>>(xf, WqT, Qb, 8192, 1024, 1024);
  gemm_bt<0><<<1024, 256, 0, stream>>>(encf, WkT, KVb, 8192, 2048, 1024);
  vtrans<<<2048, 256, 0, stream>>>(KVb, Vt);
  attn<<<1024, 256, 0, stream>>>(Qb, KVb, Vt, bias, ctxf);
  gemm_bt<1><<<512, 256, 0, stream>>>(ctxf, WoT, d_out, 8192, 1024, 1024);
}